// Round 10
// baseline (210.808 us; speedup 1.0000x reference)
//
#include <hip/hip_runtime.h>
#include <math.h>

#define NEG 0.2f
#define LNEPS 1e-5f

typedef __attribute__((ext_vector_type(8))) short bf16x8;
typedef __attribute__((ext_vector_type(8))) unsigned short u16x8;
typedef __attribute__((ext_vector_type(4))) float f32x4;
typedef __attribute__((ext_vector_type(4))) unsigned int u32x4;

__device__ __forceinline__ float lrelu(float x){ return x > 0.f ? x : NEG*x; }

__device__ __forceinline__ short f2b(float f){
  unsigned u = __float_as_uint(f);
  unsigned r = u + 0x7fffu + ((u >> 16) & 1u);
  return (short)(r >> 16);
}
__device__ __forceinline__ float b2f(unsigned short u){
  return __uint_as_float(((unsigned)u) << 16);
}
// 2x f32 -> packed bf16 pair (RNE), single instruction
__device__ __forceinline__ unsigned cvtpk(float lo, float hi){
  unsigned r;
  asm("v_cvt_pk_bf16_f32 %0, %1, %2" : "=v"(r) : "v"(lo), "v"(hi));
  return r;
}

// -------- prep: WT/WS build + deg init (fused) --------
__global__ __launch_bounds__(256) void wt_k(const float* __restrict__ W,
                                            const float* __restrict__ att_src,
                                            const float* __restrict__ att_dst,
                                            unsigned short* __restrict__ WT,
                                            unsigned short* __restrict__ WS,
                                            int* __restrict__ deg, int N){
  int b = blockIdx.x;
  if (b < 256){
    int idx = b*256 + threadIdx.x;
    int k = idx >> 8, c = idx & 255;
    WT[c*256 + k] = (unsigned short)f2b(W[idx]);
  } else if (b < 272){
    int idx = (b-256)*256 + threadIdx.x;   // 0..4095
    int col = idx >> 8;                    // 0..15 (0-7 src, 8-15 dst)
    int k   = idx & 255;
    int head = col & 7;
    const float* av = (col < 8 ? att_src : att_dst) + head*32;
    const float* wr = W + (size_t)k*256 + head*32;
    float sum = 0.f;
    #pragma unroll
    for (int c=0;c<32;c++) sum += wr[c]*av[c];
    WS[col*256 + k] = (unsigned short)f2b(sum);
  } else {
    int i = (b-272)*256 + threadIdx.x;
    if (i < N) deg[i] = 1;
  }
}

// -------- MFMA GEMM, B-in-registers; att logits as 16 extra cols (wave 0) ----
// (256,2): needs ~200 VGPR; (256,4) caps at 64 and spills (r8 lesson).
__device__ __forceinline__ void load_half(float4 nx[8], const float* p){
  #pragma unroll
  for (int s=0;s<4;s++){
    nx[2*s]   = *(const float4*)(p + s*32);
    nx[2*s+1] = *(const float4*)(p + s*32 + 4);
  }
}
__device__ __forceinline__ void cvt_half(bf16x8 af[4], const float4 nx[8]){
  #pragma unroll
  for (int s=0;s<4;s++){
    u32x4 q;
    q.x = cvtpk(nx[2*s].x,   nx[2*s].y);
    q.y = cvtpk(nx[2*s].z,   nx[2*s].w);
    q.z = cvtpk(nx[2*s+1].x, nx[2*s+1].y);
    q.w = cvtpk(nx[2*s+1].z, nx[2*s+1].w);
    af[s] = __builtin_bit_cast(bf16x8, q);
  }
}

__global__ __launch_bounds__(256, 2) void mfma_gemm_k(const float* __restrict__ A,
    const unsigned short* __restrict__ WT, const unsigned short* __restrict__ WS,
    unsigned short* __restrict__ Cb,
    float* __restrict__ a_src, float* __restrict__ a_dst, int M, int nTiles){
  int w   = threadIdx.x >> 6;
  int l   = threadIdx.x & 63;
  int l15 = l & 15;
  int kg  = l >> 4;
  int colbase = w*64;

  bf16x8 bfr[4][8];
  #pragma unroll
  for (int j=0;j<4;j++){
    const unsigned short* bp = WT + (size_t)(colbase + j*16 + l15)*256 + kg*8;
    #pragma unroll
    for (int ks=0;ks<8;ks++) bfr[j][ks] = *(const bf16x8*)(bp + ks*32);
  }
  bf16x8 bfa[8];
  if (w==0){
    const unsigned short* bp = WS + (size_t)l15*256 + kg*8;
    #pragma unroll
    for (int ks=0;ks<8;ks++) bfa[ks] = *(const bf16x8*)(bp + ks*32);
  }

  int t = blockIdx.x;
  if (t >= nTiles) return;
  int row0 = t*16 + l15;
  const float* ap = A + (size_t)(row0 < M ? row0 : M-1)*256 + kg*8;
  float4 nx[8];
  load_half(nx, ap);

  while (t < nTiles){
    f32x4 acc[4];
    #pragma unroll
    for (int j=0;j<4;j++) acc[j] = (f32x4){0.f,0.f,0.f,0.f};
    f32x4 acc_a = (f32x4){0.f,0.f,0.f,0.f};
    bf16x8 af[4];

    cvt_half(af, nx);
    load_half(nx, ap + 128);
    #pragma unroll
    for (int s=0;s<4;s++){
      #pragma unroll
      for (int j=0;j<4;j++)
        acc[j] = __builtin_amdgcn_mfma_f32_16x16x32_bf16(af[s], bfr[j][s], acc[j], 0, 0, 0);
      if (w==0)
        acc_a = __builtin_amdgcn_mfma_f32_16x16x32_bf16(af[s], bfa[s], acc_a, 0, 0, 0);
    }

    int tn = t + gridDim.x;
    int rown = tn < nTiles ? tn*16 + l15 : row0;
    const float* apn = A + (size_t)(rown < M ? rown : M-1)*256 + kg*8;

    cvt_half(af, nx);
    load_half(nx, apn);
    #pragma unroll
    for (int s=0;s<4;s++){
      #pragma unroll
      for (int j=0;j<4;j++)
        acc[j] = __builtin_amdgcn_mfma_f32_16x16x32_bf16(af[s], bfr[j][4+s], acc[j], 0, 0, 0);
      if (w==0)
        acc_a = __builtin_amdgcn_mfma_f32_16x16x32_bf16(af[s], bfa[4+s], acc_a, 0, 0, 0);
    }

    // D layout: col=l15, row=kg*4+reg. Pack row-pairs with cvt_pk (1 inst/2 elems).
    int orow_base = t*16 + kg*4;
    #pragma unroll
    for (int j=0;j<4;j++){
      #pragma unroll
      for (int rp=0;rp<2;rp++){
        unsigned pk = cvtpk(acc[j][2*rp], acc[j][2*rp+1]);
        int orow = orow_base + 2*rp;
        if (orow < M)   Cb[(size_t)orow*256     + colbase + j*16 + l15] = (unsigned short)(pk & 0xffffu);
        if (orow+1 < M) Cb[(size_t)(orow+1)*256 + colbase + j*16 + l15] = (unsigned short)(pk >> 16);
      }
    }
    if (w==0){
      #pragma unroll
      for (int rr=0;rr<4;rr++){
        int orow = orow_base + rr;
        if (orow < M){
          if (l15 < 8) a_src[(size_t)orow*8 + l15]     = acc_a[rr];
          else         a_dst[(size_t)orow*8 + l15 - 8] = acc_a[rr];
        }
      }
    }
    t = tn; row0 = rown; ap = apn;
  }
}

// -------- CSR build (self-loops folded in: deg starts at 1) --------
__global__ void deg_k(const int* __restrict__ dst, int* __restrict__ deg, int E){
  int e = blockIdx.x*blockDim.x+threadIdx.x;
  if (e<E) atomicAdd(&deg[dst[e]],1);
}

__global__ __launch_bounds__(1024) void scan1_k(const int* __restrict__ deg,
                                                int* __restrict__ off,
                                                int* __restrict__ bsum, int n){
  __shared__ int wsum[16];
  int tid=threadIdx.x, lane=tid&63, wid=tid>>6;
  int i = blockIdx.x*1024 + tid;
  int v = (i<n)?deg[i]:0;
  int x = v;
  #pragma unroll
  for (int s=1;s<64;s<<=1){ int t2=__shfl_up(x,s); if (lane>=s) x+=t2; }
  if (lane==63) wsum[wid]=x;
  __syncthreads();
  if (tid<16){
    int y=wsum[tid];
    #pragma unroll
    for (int s=1;s<16;s<<=1){ int t2=__shfl_up(y,s); if (tid>=s) y+=t2; }
    wsum[tid]=y;
  }
  __syncthreads();
  int prefix=(wid? wsum[wid-1]:0);
  if (i<n) off[i]=prefix + x - v;
  if (tid==0) bsum[blockIdx.x]=wsum[15];
}

__global__ void scan2_k(int* __restrict__ bsum, int nb, int* __restrict__ offn){
  int lane = threadIdx.x;
  int v = (lane<nb)?bsum[lane]:0;
  int x = v;
  #pragma unroll
  for (int s=1;s<64;s<<=1){ int t2=__shfl_up(x,s); if (lane>=s) x+=t2; }
  if (lane<nb) bsum[lane] = x - v;
  if (lane==63) *offn = x;
}

__global__ __launch_bounds__(1024) void scan3self_k(int* __restrict__ off,
    const int* __restrict__ bsum, int* __restrict__ sorted, int* __restrict__ cur, int n){
  int i = blockIdx.x*1024 + threadIdx.x;
  if (i>=n) return;
  int o = off[i] + bsum[blockIdx.x];
  off[i] = o;
  sorted[o] = i;
  cur[i] = 1;
}

__global__ void scatter_k(const int* __restrict__ src, const int* __restrict__ dst,
                          const int* __restrict__ off, int* __restrict__ cur,
                          int* __restrict__ sorted, int E){
  int e=blockIdx.x*blockDim.x+threadIdx.x;
  if (e<E){
    int d=dst[e];
    int pos=off[d]+atomicAdd(&cur[d],1);
    sorted[pos]=src[e];
  }
}

// -------- aggregate + softmax + LayerNorm; distributed-exp weights --------
__global__ __launch_bounds__(256) void agg5_k(const unsigned short* __restrict__ xlb,
    const float* __restrict__ a_src, const float* __restrict__ a_dst,
    const int* __restrict__ off, const int* __restrict__ sorted,
    const float* __restrict__ bias, const float* __restrict__ gamma,
    const float* __restrict__ beta, float* __restrict__ out, int n){
  int node = blockIdx.x*4 + (threadIdx.x>>6);
  if (node >= n) return;
  int lane = threadIdx.x & 63;
  int half = lane >> 5;
  int sl   = lane & 31;
  int h    = sl >> 2;          // head for accumulation (4 lanes/head)
  int hh   = lane & 7;         // head for exp duty
  int je   = lane >> 3;        // edge slot for exp duty (0..7)
  float adst_h = a_dst[(size_t)node*8 + h];
  float adst_e = a_dst[(size_t)node*8 + hh];
  int s0 = off[node], dd = off[node+1] - s0;   // includes self edge

  float acc[8] = {0.f,0.f,0.f,0.f,0.f,0.f,0.f,0.f};
  float den = 0.f;

  int i = 0;
  for (; i+8 <= dd; i += 8){
    int s[4];
    #pragma unroll
    for (int j=0;j<4;j++) s[j] = sorted[s0 + i + 2*j + half];
    int se = sorted[s0 + i + je];
    float w_l = __expf(lrelu(a_src[(size_t)se*8 + hh] + adst_e));
    float wv[4];
    #pragma unroll
    for (int j=0;j<4;j++) wv[j] = __shfl(w_l, ((2*j+half)<<3) | h);
    u16x8 u[4];
    #pragma unroll
    for (int j=0;j<4;j++) u[j] = *(const u16x8*)(xlb + (size_t)s[j]*256 + sl*8);
    #pragma unroll
    for (int j=0;j<4;j++){
      den += wv[j];
      #pragma unroll
      for (int k=0;k<8;k++) acc[k] += wv[j]*b2f((unsigned short)u[j][k]);
    }
  }
  for (; i < dd; i += 2){
    int idx = i + half;
    bool ok = idx < dd;
    int s1 = ok ? sorted[s0+idx] : node;
    float w1 = ok ? __expf(lrelu(a_src[(size_t)s1*8+h]+adst_h)) : 0.f;
    u16x8 u1 = *(const u16x8*)(xlb + (size_t)s1*256 + sl*8);
    den += w1;
    #pragma unroll
    for (int k=0;k<8;k++) acc[k] += w1*b2f((unsigned short)u1[k]);
  }

  den += __shfl_xor(den, 32);
  #pragma unroll
  for (int k=0;k<8;k++) acc[k] += __shfl_xor(acc[k], 32);

  float rd = 1.0f/den;
  float4 bia0 = *(const float4*)(bias + sl*8);
  float4 bia1 = *(const float4*)(bias + sl*8 + 4);
  float o[8];
  o[0]=acc[0]*rd+bia0.x; o[1]=acc[1]*rd+bia0.y; o[2]=acc[2]*rd+bia0.z; o[3]=acc[3]*rd+bia0.w;
  o[4]=acc[4]*rd+bia1.x; o[5]=acc[5]*rd+bia1.y; o[6]=acc[6]*rd+bia1.z; o[7]=acc[7]*rd+bia1.w;

  float sum=0.f, ssq=0.f;
  #pragma unroll
  for (int k=0;k<8;k++){ sum += o[k]; ssq += o[k]*o[k]; }
  #pragma unroll
  for (int s=1;s<32;s<<=1){ sum += __shfl_xor(sum,s); ssq += __shfl_xor(ssq,s); }
  float mean = sum*(1.0f/256.0f);
  float var  = ssq*(1.0f/256.0f) - mean*mean;
  float rstd = rsqrtf(var + LNEPS);

  int f = sl*8 + half*4;
  float4 g  = *(const float4*)(gamma + f);
  float4 be = *(const float4*)(beta + f);
  int kb = half*4;
  float4 ov;
  ov.x = (o[kb+0]-mean)*rstd*g.x+be.x;
  ov.y = (o[kb+1]-mean)*rstd*g.y+be.y;
  ov.z = (o[kb+2]-mean)*rstd*g.z+be.z;
  ov.w = (o[kb+3]-mean)*rstd*g.w+be.w;
  *(float4*)(out + (size_t)node*256 + f) = ov;
}

extern "C" void kernel_launch(void* const* d_in, const int* in_sizes, int n_in,
                              void* d_out, int out_size, void* d_ws, size_t ws_size,
                              hipStream_t stream){
  const float* x       = (const float*)d_in[0];
  const int*   ei      = (const int*)  d_in[1];
  const float* W       = (const float*)d_in[2];
  const float* att_src = (const float*)d_in[3];
  const float* att_dst = (const float*)d_in[4];
  const float* bias    = (const float*)d_in[5];
  const float* gamma   = (const float*)d_in[6];
  const float* beta    = (const float*)d_in[7];
  float* out = (float*)d_out;

  int N = in_sizes[0]/256;
  int E = in_sizes[1]/2;
  const int* srcp = ei;
  const int* dstp = ei + E;

  unsigned short* xlb = (unsigned short*)d_ws;               // N*256 bf16
  float* a_src = (float*)(xlb + (size_t)N*256);
  float* a_dst = a_src + (size_t)N*8;
  int*   deg   = (int*)(a_dst + (size_t)N*8);
  int*   off   = deg + N;
  int*   cur   = off + N + 1;
  int*   sorted= cur + N;                                    // E+N entries
  int*   bsum  = sorted + E + N;
  unsigned short* WT = (unsigned short*)(bsum + 1024);
  unsigned short* WS = WT + 65536;                           // 16*256 bf16

  int nb = (N + 1023)/1024;
  int nbI = (N + 255)/256;
  int nTiles = (N + 15)/16;

  wt_k<<<272 + nbI, 256, 0, stream>>>(W, att_src, att_dst, WT, WS, deg, N);
  mfma_gemm_k<<<512, 256, 0, stream>>>(x, WT, WS, xlb, a_src, a_dst, N, nTiles);
  deg_k<<<(E+255)/256, 256, 0, stream>>>(dstp, deg, E);
  scan1_k<<<nb, 1024, 0, stream>>>(deg, off, bsum, N);
  scan2_k<<<1, 64, 0, stream>>>(bsum, nb, off + N);
  scan3self_k<<<nb, 1024, 0, stream>>>(off, bsum, sorted, cur, N);
  scatter_k<<<(E+255)/256, 256, 0, stream>>>(srcp, dstp, off, cur, sorted, E);
  agg5_k<<<(N+3)/4, 256, 0, stream>>>(xlb, a_src, a_dst, off, sorted, bias, gamma, beta, out, N);
}

// Round 11
// 193.905 us; speedup vs baseline: 1.0872x; 1.0872x over previous
//
#include <hip/hip_runtime.h>
#include <math.h>

#define NEG 0.2f
#define LNEPS 1e-5f

typedef __attribute__((ext_vector_type(8))) short bf16x8;
typedef __attribute__((ext_vector_type(8))) unsigned short u16x8;
typedef __attribute__((ext_vector_type(4))) float f32x4;
typedef __attribute__((ext_vector_type(4))) unsigned int u32x4;

__device__ __forceinline__ float lrelu(float x){ return x > 0.f ? x : NEG*x; }

__device__ __forceinline__ short f2b(float f){
  unsigned u = __float_as_uint(f);
  unsigned r = u + 0x7fffu + ((u >> 16) & 1u);
  return (short)(r >> 16);
}
__device__ __forceinline__ float b2f(unsigned short u){
  return __uint_as_float(((unsigned)u) << 16);
}
// 2x f32 -> packed bf16 pair (RNE), single instruction
__device__ __forceinline__ unsigned cvtpk(float lo, float hi){
  unsigned r;
  asm("v_cvt_pk_bf16_f32 %0, %1, %2" : "=v"(r) : "v"(lo), "v"(hi));
  return r;
}

// -------- prep: WT/WS build + deg histogram (deg pre-zeroed by memset) --------
__global__ __launch_bounds__(256) void wt_k(const float* __restrict__ W,
                                            const float* __restrict__ att_src,
                                            const float* __restrict__ att_dst,
                                            const int* __restrict__ dst,
                                            unsigned short* __restrict__ WT,
                                            unsigned short* __restrict__ WS,
                                            int* __restrict__ deg, int E){
  int b = blockIdx.x;
  if (b < 256){
    int idx = b*256 + threadIdx.x;
    int k = idx >> 8, c = idx & 255;
    WT[c*256 + k] = (unsigned short)f2b(W[idx]);
  } else if (b < 272){
    int idx = (b-256)*256 + threadIdx.x;   // 0..4095
    int col = idx >> 8;                    // 0..15 (0-7 src, 8-15 dst)
    int k   = idx & 255;
    int head = col & 7;
    const float* av = (col < 8 ? att_src : att_dst) + head*32;
    const float* wr = W + (size_t)k*256 + head*32;
    float sum = 0.f;
    #pragma unroll
    for (int c2=0;c2<32;c2++) sum += wr[c2]*av[c2];
    WS[col*256 + k] = (unsigned short)f2b(sum);
  } else {
    int e = (b-272)*256 + threadIdx.x;
    if (e < E) atomicAdd(&deg[dst[e]], 1);
  }
}

// -------- MFMA GEMM: LDS-staged A (shared by all 4 waves), B-in-registers ----
// A-tile 16x256 f32 loaded coalesced -> bf16 -> XOR-swizzled 8KB LDS.
// Swizzle: 16B-slot s' = s ^ ((s>>5)&7)  (row = s>>5; spreads ds_read banks).
__device__ __forceinline__ void load_tile(float4 v[4], const float* __restrict__ A,
                                          int t, int M, int tid){
  const float* base = A + (size_t)t*4096;
  int rmax = M - 1 - t*16;                 // >= 0 (t < nTiles)
  #pragma unroll
  for (int j=0;j<4;j++){
    int idx4 = (j>>1)*512 + 2*tid + (j&1); // float4 index within tile
    int r = idx4 >> 6;
    if (r > rmax) idx4 = (rmax<<6) | (idx4 & 63);
    v[j] = *(const float4*)(base + (size_t)idx4*4);
  }
}

__global__ __launch_bounds__(256, 2) void mfma_gemm_k(const float* __restrict__ A,
    const unsigned short* __restrict__ WT, const unsigned short* __restrict__ WS,
    unsigned short* __restrict__ Cb,
    float* __restrict__ a_src, float* __restrict__ a_dst, int M, int nTiles){
  __shared__ __align__(16) unsigned short Asb[16*256];   // 8KB bf16, swizzled
  int tid = threadIdx.x;
  int w   = tid >> 6;
  int l   = tid & 63;
  int l15 = l & 15;
  int kg  = l >> 4;
  int colbase = w*64;

  bf16x8 bfr[4][8];
  #pragma unroll
  for (int j=0;j<4;j++){
    const unsigned short* bp = WT + (size_t)(colbase + j*16 + l15)*256 + kg*8;
    #pragma unroll
    for (int ks=0;ks<8;ks++) bfr[j][ks] = *(const bf16x8*)(bp + ks*32);
  }
  bf16x8 bfa[8];
  if (w==0){
    const unsigned short* bp = WS + (size_t)l15*256 + kg*8;
    #pragma unroll
    for (int ks=0;ks<8;ks++) bfa[ks] = *(const bf16x8*)(bp + ks*32);
  }

  int t = blockIdx.x;
  if (t >= nTiles) return;
  float4 v[4];
  load_tile(v, A, t, M, tid);

  while (t < nTiles){
    __syncthreads();                        // prev-tile LDS reads done
    // stage: 8 cvt_pk + 2 ds_write_b128 per thread
    #pragma unroll
    for (int p=0;p<2;p++){
      u32x4 q;
      q.x = cvtpk(v[2*p].x,   v[2*p].y);
      q.y = cvtpk(v[2*p].z,   v[2*p].w);
      q.z = cvtpk(v[2*p+1].x, v[2*p+1].y);
      q.w = cvtpk(v[2*p+1].z, v[2*p+1].w);
      int slot = p*256 + tid;
      int sw = slot ^ ((slot>>5)&7);
      *(u32x4*)(Asb + (size_t)sw*8) = q;
    }
    __syncthreads();                        // LDS tile ready

    int tn = t + gridDim.x;
    if (tn < nTiles) load_tile(v, A, tn, M, tid);   // prefetch (hidden under MFMA)

    f32x4 acc[4];
    #pragma unroll
    for (int j=0;j<4;j++) acc[j] = (f32x4){0.f,0.f,0.f,0.f};
    f32x4 acc_a = (f32x4){0.f,0.f,0.f,0.f};

    #pragma unroll
    for (int s=0;s<8;s++){
      int slot = l15*32 + kg + s*4;
      int sw = slot ^ (l15 & 7);            // (slot>>5)&7 == l15&7
      bf16x8 af = *(const bf16x8*)(Asb + (size_t)sw*8);
      #pragma unroll
      for (int j=0;j<4;j++)
        acc[j] = __builtin_amdgcn_mfma_f32_16x16x32_bf16(af, bfr[j][s], acc[j], 0, 0, 0);
      if (w==0)
        acc_a = __builtin_amdgcn_mfma_f32_16x16x32_bf16(af, bfa[s], acc_a, 0, 0, 0);
    }

    // D layout: col=l15, row=kg*4+reg. Pack row-pairs with cvt_pk.
    int orow_base = t*16 + kg*4;
    #pragma unroll
    for (int j=0;j<4;j++){
      #pragma unroll
      for (int rp=0;rp<2;rp++){
        unsigned pk = cvtpk(acc[j][2*rp], acc[j][2*rp+1]);
        int orow = orow_base + 2*rp;
        if (orow < M)   Cb[(size_t)orow*256     + colbase + j*16 + l15] = (unsigned short)(pk & 0xffffu);
        if (orow+1 < M) Cb[(size_t)(orow+1)*256 + colbase + j*16 + l15] = (unsigned short)(pk >> 16);
      }
    }
    if (w==0){
      #pragma unroll
      for (int rr=0;rr<4;rr++){
        int orow = orow_base + rr;
        if (orow < M){
          if (l15 < 8) a_src[(size_t)orow*8 + l15]     = acc_a[rr];
          else         a_dst[(size_t)orow*8 + l15 - 8] = acc_a[rr];
        }
      }
    }
    t = tn;
  }
}

// -------- CSR: scan of (deg[i]+1) absorbs self-loops --------
__global__ __launch_bounds__(1024) void scan1_k(const int* __restrict__ deg,
                                                int* __restrict__ off,
                                                int* __restrict__ bsum, int n){
  __shared__ int wsum[16];
  int tid=threadIdx.x, lane=tid&63, wid=tid>>6;
  int i = blockIdx.x*1024 + tid;
  int v = (i<n)?(deg[i]+1):0;
  int x = v;
  #pragma unroll
  for (int s=1;s<64;s<<=1){ int t2=__shfl_up(x,s); if (lane>=s) x+=t2; }
  if (lane==63) wsum[wid]=x;
  __syncthreads();
  if (tid<16){
    int y=wsum[tid];
    #pragma unroll
    for (int s=1;s<16;s<<=1){ int t2=__shfl_up(y,s); if (tid>=s) y+=t2; }
    wsum[tid]=y;
  }
  __syncthreads();
  int prefix=(wid? wsum[wid-1]:0);
  if (i<n) off[i]=prefix + x - v;
  if (tid==0) bsum[blockIdx.x]=wsum[15];
}

// finalize offsets (inline block-sum prefix via wave reduce) + plant self edge
__global__ __launch_bounds__(1024) void scan3self_k(int* __restrict__ off,
    const int* __restrict__ bsum, int* __restrict__ sorted, int* __restrict__ cur,
    int n, int total){
  __shared__ int prefs;
  if (threadIdx.x < 64){
    int v = ((int)threadIdx.x < blockIdx.x) ? bsum[threadIdx.x] : 0;  // nb<=64
    #pragma unroll
    for (int s=1;s<64;s<<=1) v += __shfl_xor(v, s);
    if (threadIdx.x==0) prefs = v;
  }
  __syncthreads();
  int i = blockIdx.x*1024 + threadIdx.x;
  if (blockIdx.x==0 && threadIdx.x==0) off[n] = total;
  if (i>=n) return;
  int o = off[i] + prefs;
  off[i] = o;
  sorted[o] = i;
  cur[i] = 1;
}

__global__ void scatter_k(const int* __restrict__ src, const int* __restrict__ dst,
                          const int* __restrict__ off, int* __restrict__ cur,
                          int* __restrict__ sorted, int E){
  int e=blockIdx.x*blockDim.x+threadIdx.x;
  if (e<E){
    int d=dst[e];
    int pos=off[d]+atomicAdd(&cur[d],1);
    sorted[pos]=src[e];
  }
}

// -------- aggregate + softmax + LayerNorm; distributed-exp weights --------
__global__ __launch_bounds__(256) void agg5_k(const unsigned short* __restrict__ xlb,
    const float* __restrict__ a_src, const float* __restrict__ a_dst,
    const int* __restrict__ off, const int* __restrict__ sorted,
    const float* __restrict__ bias, const float* __restrict__ gamma,
    const float* __restrict__ beta, float* __restrict__ out, int n){
  int node = blockIdx.x*4 + (threadIdx.x>>6);
  if (node >= n) return;
  int lane = threadIdx.x & 63;
  int half = lane >> 5;
  int sl   = lane & 31;
  int h    = sl >> 2;          // head for accumulation (4 lanes/head)
  int hh   = lane & 7;         // head for exp duty
  int je   = lane >> 3;        // edge slot for exp duty (0..7)
  float adst_h = a_dst[(size_t)node*8 + h];
  float adst_e = a_dst[(size_t)node*8 + hh];
  int s0 = off[node], dd = off[node+1] - s0;   // includes self edge

  float acc[8] = {0.f,0.f,0.f,0.f,0.f,0.f,0.f,0.f};
  float den = 0.f;

  int i = 0;
  for (; i+8 <= dd; i += 8){
    int s[4];
    #pragma unroll
    for (int j=0;j<4;j++) s[j] = sorted[s0 + i + 2*j + half];
    int se = sorted[s0 + i + je];
    float w_l = __expf(lrelu(a_src[(size_t)se*8 + hh] + adst_e));
    float wv[4];
    #pragma unroll
    for (int j=0;j<4;j++) wv[j] = __shfl(w_l, ((2*j+half)<<3) | h);
    u16x8 u[4];
    #pragma unroll
    for (int j=0;j<4;j++) u[j] = *(const u16x8*)(xlb + (size_t)s[j]*256 + sl*8);
    #pragma unroll
    for (int j=0;j<4;j++){
      den += wv[j];
      #pragma unroll
      for (int k=0;k<8;k++) acc[k] += wv[j]*b2f((unsigned short)u[j][k]);
    }
  }
  for (; i < dd; i += 2){
    int idx = i + half;
    bool ok = idx < dd;
    int s1 = ok ? sorted[s0+idx] : node;
    float w1 = ok ? __expf(lrelu(a_src[(size_t)s1*8+h]+adst_h)) : 0.f;
    u16x8 u1 = *(const u16x8*)(xlb + (size_t)s1*256 + sl*8);
    den += w1;
    #pragma unroll
    for (int k=0;k<8;k++) acc[k] += w1*b2f((unsigned short)u1[k]);
  }

  den += __shfl_xor(den, 32);
  #pragma unroll
  for (int k=0;k<8;k++) acc[k] += __shfl_xor(acc[k], 32);

  float rd = 1.0f/den;
  float4 bia0 = *(const float4*)(bias + sl*8);
  float4 bia1 = *(const float4*)(bias + sl*8 + 4);
  float o[8];
  o[0]=acc[0]*rd+bia0.x; o[1]=acc[1]*rd+bia0.y; o[2]=acc[2]*rd+bia0.z; o[3]=acc[3]*rd+bia0.w;
  o[4]=acc[4]*rd+bia1.x; o[5]=acc[5]*rd+bia1.y; o[6]=acc[6]*rd+bia1.z; o[7]=acc[7]*rd+bia1.w;

  float sum=0.f, ssq=0.f;
  #pragma unroll
  for (int k=0;k<8;k++){ sum += o[k]; ssq += o[k]*o[k]; }
  #pragma unroll
  for (int s=1;s<32;s<<=1){ sum += __shfl_xor(sum,s); ssq += __shfl_xor(ssq,s); }
  float mean = sum*(1.0f/256.0f);
  float var  = ssq*(1.0f/256.0f) - mean*mean;
  float rstd = rsqrtf(var + LNEPS);

  int f = sl*8 + half*4;
  float4 g  = *(const float4*)(gamma + f);
  float4 be = *(const float4*)(beta + f);
  int kb = half*4;
  float4 ov;
  ov.x = (o[kb+0]-mean)*rstd*g.x+be.x;
  ov.y = (o[kb+1]-mean)*rstd*g.y+be.y;
  ov.z = (o[kb+2]-mean)*rstd*g.z+be.z;
  ov.w = (o[kb+3]-mean)*rstd*g.w+be.w;
  *(float4*)(out + (size_t)node*256 + f) = ov;
}

extern "C" void kernel_launch(void* const* d_in, const int* in_sizes, int n_in,
                              void* d_out, int out_size, void* d_ws, size_t ws_size,
                              hipStream_t stream){
  const float* x       = (const float*)d_in[0];
  const int*   ei      = (const int*)  d_in[1];
  const float* W       = (const float*)d_in[2];
  const float* att_src = (const float*)d_in[3];
  const float* att_dst = (const float*)d_in[4];
  const float* bias    = (const float*)d_in[5];
  const float* gamma   = (const float*)d_in[6];
  const float* beta    = (const float*)d_in[7];
  float* out = (float*)d_out;

  int N = in_sizes[0]/256;
  int E = in_sizes[1]/2;
  const int* srcp = ei;
  const int* dstp = ei + E;

  unsigned short* xlb = (unsigned short*)d_ws;               // N*256 bf16
  float* a_src = (float*)(xlb + (size_t)N*256);
  float* a_dst = a_src + (size_t)N*8;
  int*   deg   = (int*)(a_dst + (size_t)N*8);
  int*   off   = deg + N;
  int*   cur   = off + N + 1;
  int*   sorted= cur + N;                                    // E+N entries
  int*   bsum  = sorted + E + N;
  unsigned short* WT = (unsigned short*)(bsum + 1024);
  unsigned short* WS = WT + 65536;                           // 16*256 bf16

  int nb = (N + 1023)/1024;
  int nTiles = (N + 15)/16;

  hipMemsetAsync(deg, 0, (size_t)N*sizeof(int), stream);
  wt_k<<<272 + (E+255)/256, 256, 0, stream>>>(W, att_src, att_dst, dstp, WT, WS, deg, E);
  mfma_gemm_k<<<512, 256, 0, stream>>>(x, WT, WS, xlb, a_src, a_dst, N, nTiles);
  scan1_k<<<nb, 1024, 0, stream>>>(deg, off, bsum, N);
  scan3self_k<<<nb, 1024, 0, stream>>>(off, bsum, sorted, cur, N, E + N);
  scatter_k<<<(E+255)/256, 256, 0, stream>>>(srcp, dstp, off, cur, sorted, E);
  agg5_k<<<(N+3)/4, 256, 0, stream>>>(xlb, a_src, a_dst, off, sorted, bias, gamma, beta, out, N);
}

// Round 12
// 183.904 us; speedup vs baseline: 1.1463x; 1.0544x over previous
//
#include <hip/hip_runtime.h>
#include <math.h>

#define NEG 0.2f
#define LNEPS 1e-5f
#define GB 512   // gemm blocks in fused kernel; blocks >= GB do edge scatter

typedef __attribute__((ext_vector_type(8))) short bf16x8;
typedef __attribute__((ext_vector_type(8))) unsigned short u16x8;
typedef __attribute__((ext_vector_type(4))) float f32x4;
typedef __attribute__((ext_vector_type(4))) unsigned int u32x4;

__device__ __forceinline__ float lrelu(float x){ return x > 0.f ? x : NEG*x; }

__device__ __forceinline__ short f2b(float f){
  unsigned u = __float_as_uint(f);
  unsigned r = u + 0x7fffu + ((u >> 16) & 1u);
  return (short)(r >> 16);
}
__device__ __forceinline__ float b2f(unsigned short u){
  return __uint_as_float(((unsigned)u) << 16);
}
__device__ __forceinline__ unsigned cvtpk(float lo, float hi){
  unsigned r;
  asm("v_cvt_pk_bf16_f32 %0, %1, %2" : "=v"(r) : "v"(lo), "v"(hi));
  return r;
}

// -------- prep: WT/WS build + deg histogram (deg pre-zeroed by memset) --------
__global__ __launch_bounds__(256) void wt_k(const float* __restrict__ W,
                                            const float* __restrict__ att_src,
                                            const float* __restrict__ att_dst,
                                            const int* __restrict__ dst,
                                            unsigned short* __restrict__ WT,
                                            unsigned short* __restrict__ WS,
                                            int* __restrict__ deg, int E){
  int b = blockIdx.x;
  if (b < 256){
    int idx = b*256 + threadIdx.x;
    int k = idx >> 8, c = idx & 255;
    WT[c*256 + k] = (unsigned short)f2b(W[idx]);
  } else if (b < 272){
    int idx = (b-256)*256 + threadIdx.x;   // 0..4095
    int col = idx >> 8;                    // 0..15 (0-7 src, 8-15 dst)
    int k   = idx & 255;
    int head = col & 7;
    const float* av = (col < 8 ? att_src : att_dst) + head*32;
    const float* wr = W + (size_t)k*256 + head*32;
    float sum = 0.f;
    #pragma unroll
    for (int c2=0;c2<32;c2++) sum += wr[c2]*av[c2];
    WS[col*256 + k] = (unsigned short)f2b(sum);
  } else {
    int e = (b-272)*256 + threadIdx.x;
    if (e < E) atomicAdd(&deg[dst[e]], 1);
  }
}

// -------- CSR: scan of (deg[i]+1) absorbs self-loops --------
__global__ __launch_bounds__(1024) void scan1_k(const int* __restrict__ deg,
                                                int* __restrict__ off,
                                                int* __restrict__ bsum, int n){
  __shared__ int wsum[16];
  int tid=threadIdx.x, lane=tid&63, wid=tid>>6;
  int i = blockIdx.x*1024 + tid;
  int v = (i<n)?(deg[i]+1):0;
  int x = v;
  #pragma unroll
  for (int s=1;s<64;s<<=1){ int t2=__shfl_up(x,s); if (lane>=s) x+=t2; }
  if (lane==63) wsum[wid]=x;
  __syncthreads();
  if (tid<16){
    int y=wsum[tid];
    #pragma unroll
    for (int s=1;s<16;s<<=1){ int t2=__shfl_up(y,s); if (tid>=s) y+=t2; }
    wsum[tid]=y;
  }
  __syncthreads();
  int prefix=(wid? wsum[wid-1]:0);
  if (i<n) off[i]=prefix + x - v;
  if (tid==0) bsum[blockIdx.x]=wsum[15];
}

// finalize offsets (inline block-sum prefix) + plant self edge, cur=1
__global__ __launch_bounds__(1024) void scan3self_k(int* __restrict__ off,
    const int* __restrict__ bsum, int* __restrict__ sorted, int* __restrict__ cur,
    int n, int total){
  __shared__ int prefs;
  if (threadIdx.x < 64){
    int v = ((int)threadIdx.x < blockIdx.x) ? bsum[threadIdx.x] : 0;  // nb<=64
    #pragma unroll
    for (int s=1;s<64;s<<=1) v += __shfl_xor(v, s);
    if (threadIdx.x==0) prefs = v;
  }
  __syncthreads();
  int i = blockIdx.x*1024 + threadIdx.x;
  if (blockIdx.x==0 && threadIdx.x==0) off[n] = total;
  if (i>=n) return;
  int o = off[i] + prefs;
  off[i] = o;
  sorted[o] = i;
  cur[i] = 1;
}

// -------- fused MFMA GEMM (blocks < GB) + edge scatter (blocks >= GB) --------
// GEMM: LDS-staged A, B-in-registers, SWAPPED mfma operands so each lane owns
// 4 consecutive cols of ONE row -> coalesced uint2 C-stores, float4 asd store.
__device__ __forceinline__ void load_tile(float4 v[4], const float* __restrict__ A,
                                          int t, int M, int tid){
  const float* base = A + (size_t)t*4096;
  int rmax = M - 1 - t*16;
  #pragma unroll
  for (int j=0;j<4;j++){
    int idx4 = (j>>1)*512 + 2*tid + (j&1);
    int r = idx4 >> 6;
    if (r > rmax) idx4 = (rmax<<6) | (idx4 & 63);
    v[j] = *(const float4*)(base + (size_t)idx4*4);
  }
}

__global__ __launch_bounds__(256, 2) void gemm_scat_k(const float* __restrict__ A,
    const unsigned short* __restrict__ WT, const unsigned short* __restrict__ WS,
    unsigned short* __restrict__ Cb, float* __restrict__ asd, int M, int nTiles,
    const int* __restrict__ src, const int* __restrict__ dst,
    const int* __restrict__ off, int* __restrict__ cur,
    int* __restrict__ sorted, int E){
  __shared__ __align__(16) unsigned short Asb[16*256];   // 8KB bf16, swizzled
  int tid = threadIdx.x;

  if (blockIdx.x >= GB){       // ---- scatter role ----
    int e = (blockIdx.x - GB)*256 + tid;
    if (e < E){
      int d = dst[e];
      int pos = off[d] + atomicAdd(&cur[d], 1);
      sorted[pos] = src[e];
    }
    return;
  }

  // ---- gemm role ----
  int w   = tid >> 6;
  int l   = tid & 63;
  int l15 = l & 15;
  int kg  = l >> 4;
  int colbase = w*64;

  bf16x8 bfr[4][8];
  #pragma unroll
  for (int j=0;j<4;j++){
    const unsigned short* bp = WT + (size_t)(colbase + j*16 + l15)*256 + kg*8;
    #pragma unroll
    for (int ks=0;ks<8;ks++) bfr[j][ks] = *(const bf16x8*)(bp + ks*32);
  }
  bf16x8 bfa[8];
  if (w==0){
    const unsigned short* bp = WS + (size_t)l15*256 + kg*8;
    #pragma unroll
    for (int ks=0;ks<8;ks++) bfa[ks] = *(const bf16x8*)(bp + ks*32);
  }

  int t = blockIdx.x;
  if (t >= nTiles) return;
  float4 v[4];
  load_tile(v, A, t, M, tid);

  while (t < nTiles){
    __syncthreads();
    #pragma unroll
    for (int p=0;p<2;p++){
      u32x4 q;
      q.x = cvtpk(v[2*p].x,   v[2*p].y);
      q.y = cvtpk(v[2*p].z,   v[2*p].w);
      q.z = cvtpk(v[2*p+1].x, v[2*p+1].y);
      q.w = cvtpk(v[2*p+1].z, v[2*p+1].w);
      int slot = p*256 + tid;
      int sw = slot ^ ((slot>>5)&7);
      *(u32x4*)(Asb + (size_t)sw*8) = q;
    }
    __syncthreads();

    int tn = t + GB;
    if (tn < nTiles) load_tile(v, A, tn, M, tid);

    f32x4 acc[4];
    #pragma unroll
    for (int j=0;j<4;j++) acc[j] = (f32x4){0.f,0.f,0.f,0.f};
    f32x4 acc_a = (f32x4){0.f,0.f,0.f,0.f};

    #pragma unroll
    for (int s=0;s<8;s++){
      int slot = l15*32 + kg + s*4;
      int sw = slot ^ (l15 & 7);
      bf16x8 af = *(const bf16x8*)(Asb + (size_t)sw*8);
      // SWAPPED operands: D^T fragment -> lane (l15,kg) owns row t*16+l15,
      // cols colbase + j*16 + kg*4 + [0..3]
      #pragma unroll
      for (int j=0;j<4;j++)
        acc[j] = __builtin_amdgcn_mfma_f32_16x16x32_bf16(bfr[j][s], af, acc[j], 0, 0, 0);
      if (w==0)
        acc_a = __builtin_amdgcn_mfma_f32_16x16x32_bf16(bfa[s], af, acc_a, 0, 0, 0);
    }

    int row = t*16 + l15;
    if (row < M){
      unsigned short* cp = Cb + (size_t)row*256 + colbase + kg*4;
      #pragma unroll
      for (int j=0;j<4;j++){
        uint2 pk;
        pk.x = cvtpk(acc[j][0], acc[j][1]);
        pk.y = cvtpk(acc[j][2], acc[j][3]);
        *(uint2*)(cp + j*16) = pk;
      }
      if (w==0){
        float4 av = {acc_a[0], acc_a[1], acc_a[2], acc_a[3]};
        *(float4*)(asd + (size_t)row*16 + kg*4) = av;   // cols kg*4..+3 (0-7 src, 8-15 dst)
      }
    }
    t = tn;
  }
}

// -------- aggregate + softmax + LayerNorm; distributed-exp weights --------
__global__ __launch_bounds__(256) void agg5_k(const unsigned short* __restrict__ xlb,
    const float* __restrict__ asd,
    const int* __restrict__ off, const int* __restrict__ sorted,
    const float* __restrict__ bias, const float* __restrict__ gamma,
    const float* __restrict__ beta, float* __restrict__ out, int n){
  int node = blockIdx.x*4 + (threadIdx.x>>6);
  if (node >= n) return;
  int lane = threadIdx.x & 63;
  int half = lane >> 5;
  int sl   = lane & 31;
  int h    = sl >> 2;          // head for accumulation (4 lanes/head)
  int hh   = lane & 7;         // head for exp duty
  int je   = lane >> 3;        // edge slot for exp duty (0..7)
  float adst_h = asd[(size_t)node*16 + 8 + h];
  float adst_e = asd[(size_t)node*16 + 8 + hh];
  int s0 = off[node], dd = off[node+1] - s0;   // includes self edge

  float acc[8] = {0.f,0.f,0.f,0.f,0.f,0.f,0.f,0.f};
  float den = 0.f;

  int i = 0;
  for (; i+8 <= dd; i += 8){
    int s[4];
    #pragma unroll
    for (int j=0;j<4;j++) s[j] = sorted[s0 + i + 2*j + half];
    int se = sorted[s0 + i + je];
    float w_l = __expf(lrelu(asd[(size_t)se*16 + hh] + adst_e));
    float wv[4];
    #pragma unroll
    for (int j=0;j<4;j++) wv[j] = __shfl(w_l, ((2*j+half)<<3) | h);
    u16x8 u[4];
    #pragma unroll
    for (int j=0;j<4;j++) u[j] = *(const u16x8*)(xlb + (size_t)s[j]*256 + sl*8);
    #pragma unroll
    for (int j=0;j<4;j++){
      den += wv[j];
      #pragma unroll
      for (int k=0;k<8;k++) acc[k] += wv[j]*b2f((unsigned short)u[j][k]);
    }
  }
  for (; i < dd; i += 2){
    int idx = i + half;
    bool ok = idx < dd;
    int s1 = ok ? sorted[s0+idx] : node;
    float w1 = ok ? __expf(lrelu(asd[(size_t)s1*16 + h] + adst_h)) : 0.f;
    u16x8 u1 = *(const u16x8*)(xlb + (size_t)s1*256 + sl*8);
    den += w1;
    #pragma unroll
    for (int k=0;k<8;k++) acc[k] += w1*b2f((unsigned short)u1[k]);
  }

  den += __shfl_xor(den, 32);
  #pragma unroll
  for (int k=0;k<8;k++) acc[k] += __shfl_xor(acc[k], 32);

  float rd = 1.0f/den;
  float4 bia0 = *(const float4*)(bias + sl*8);
  float4 bia1 = *(const float4*)(bias + sl*8 + 4);
  float o[8];
  o[0]=acc[0]*rd+bia0.x; o[1]=acc[1]*rd+bia0.y; o[2]=acc[2]*rd+bia0.z; o[3]=acc[3]*rd+bia0.w;
  o[4]=acc[4]*rd+bia1.x; o[5]=acc[5]*rd+bia1.y; o[6]=acc[6]*rd+bia1.z; o[7]=acc[7]*rd+bia1.w;

  float sum=0.f, ssq=0.f;
  #pragma unroll
  for (int k=0;k<8;k++){ sum += o[k]; ssq += o[k]*o[k]; }
  #pragma unroll
  for (int s=1;s<32;s<<=1){ sum += __shfl_xor(sum,s); ssq += __shfl_xor(ssq,s); }
  float mean = sum*(1.0f/256.0f);
  float var  = ssq*(1.0f/256.0f) - mean*mean;
  float rstd = rsqrtf(var + LNEPS);

  int f = sl*8 + half*4;
  float4 g  = *(const float4*)(gamma + f);
  float4 be = *(const float4*)(beta + f);
  int kb = half*4;
  float4 ov;
  ov.x = (o[kb+0]-mean)*rstd*g.x+be.x;
  ov.y = (o[kb+1]-mean)*rstd*g.y+be.y;
  ov.z = (o[kb+2]-mean)*rstd*g.z+be.z;
  ov.w = (o[kb+3]-mean)*rstd*g.w+be.w;
  *(float4*)(out + (size_t)node*256 + f) = ov;
}

extern "C" void kernel_launch(void* const* d_in, const int* in_sizes, int n_in,
                              void* d_out, int out_size, void* d_ws, size_t ws_size,
                              hipStream_t stream){
  const float* x       = (const float*)d_in[0];
  const int*   ei      = (const int*)  d_in[1];
  const float* W       = (const float*)d_in[2];
  const float* att_src = (const float*)d_in[3];
  const float* att_dst = (const float*)d_in[4];
  const float* bias    = (const float*)d_in[5];
  const float* gamma   = (const float*)d_in[6];
  const float* beta    = (const float*)d_in[7];
  float* out = (float*)d_out;

  int N = in_sizes[0]/256;
  int E = in_sizes[1]/2;
  const int* srcp = ei;
  const int* dstp = ei + E;

  unsigned short* xlb = (unsigned short*)d_ws;               // N*256 bf16
  float* asd   = (float*)(xlb + (size_t)N*256);              // N*16 f32 (src|dst logits)
  int*   deg   = (int*)(asd + (size_t)N*16);
  int*   off   = deg + N;
  int*   cur   = off + N + 1;
  int*   sorted= cur + N;                                    // E+N entries
  int*   bsum  = sorted + E + N;
  unsigned short* WT = (unsigned short*)(bsum + 1024);
  unsigned short* WS = WT + 65536;                           // 16*256 bf16

  int nb = (N + 1023)/1024;
  int nTiles = (N + 15)/16;
  int scatBlocks = (E + 255)/256;

  hipMemsetAsync(deg, 0, (size_t)N*sizeof(int), stream);
  wt_k<<<272 + scatBlocks, 256, 0, stream>>>(W, att_src, att_dst, dstp, WT, WS, deg, E);
  scan1_k<<<nb, 1024, 0, stream>>>(deg, off, bsum, N);
  scan3self_k<<<nb, 1024, 0, stream>>>(off, bsum, sorted, cur, N, E + N);
  gemm_scat_k<<<GB + scatBlocks, 256, 0, stream>>>(x, WT, WS, xlb, asd, N, nTiles,
                                                   srcp, dstp, off, cur, sorted, E);
  agg5_k<<<(N+3)/4, 256, 0, stream>>>(xlb, asd, off, sorted, bias, gamma, beta, out, N);
}